// Round 1
// baseline (493.037 us; speedup 1.0000x reference)
//
#include <hip/hip_runtime.h>
#include <math.h>

#define MIN_NORM 1e-15f
#define MAX_NORM 0.99999f   /* 1 - 1e-5 */
#define EPSF     1e-6f

__device__ __forceinline__ float dot4(float4 a, float4 b) {
    return a.x*b.x + a.y*b.y + a.z*b.z + a.w*b.w;
}

// sum across the 8 lanes of an 8-lane group (each row = 8 lanes x float4)
__device__ __forceinline__ float grp8(float v) {
    v += __shfl_xor(v, 1, 8);
    v += __shfl_xor(v, 2, 8);
    v += __shfl_xor(v, 4, 8);
    return v;
}

// sum across 32 lanes (finish kernels run 32 threads)
__device__ __forceinline__ float sum32(float v) {
    v += __shfl_xor(v, 1, 32);
    v += __shfl_xor(v, 2, 32);
    v += __shfl_xor(v, 4, 32);
    v += __shfl_xor(v, 8, 32);
    v += __shfl_xor(v, 16, 32);
    return v;
}

// MODE 0: sum_i log0(x_i)            -> acc[0..31]
// MODE 1: sum_i log_map(mu, x_i)     -> acc[0..31]
// MODE 2: sum_i (2*atanh(|w_i|))^2   -> acc[0]
template <int MODE>
__global__ __launch_bounds__(256) void reduce_kernel(const float4* __restrict__ x4,
                                                     const float* __restrict__ muv,
                                                     float* __restrict__ acc,
                                                     int nrows)
{
    const int l8   = threadIdx.x & 7;
    const int grp0 = (int)(blockIdx.x * blockDim.x + threadIdx.x) >> 3;
    const int ngrp = (int)(gridDim.x * blockDim.x) >> 3;

    float4 mu4 = make_float4(0.f, 0.f, 0.f, 0.f);
    float mu2 = 0.f, cb = 1.f;
    if constexpr (MODE != 0) {
        mu4 = reinterpret_cast<const float4*>(muv)[l8];
        mu2 = grp8(dot4(mu4, mu4));
        cb  = 1.f - mu2;
    }

    float4 a = make_float4(0.f, 0.f, 0.f, 0.f);
    float av = 0.f;

    for (int row = grp0; row < nrows; row += ngrp) {
        float4 xi = x4[row * 8 + l8];
        if constexpr (MODE == 0) {
            float n2 = grp8(dot4(xi, xi));
            float n  = fminf(fmaxf(sqrtf(n2), MIN_NORM), MAX_NORM);
            float s  = atanhf(n) / n;
            a.x += s * xi.x; a.y += s * xi.y; a.z += s * xi.z; a.w += s * xi.w;
        } else {
            float xi2   = grp8(dot4(xi, xi));
            float dmx   = grp8(dot4(mu4, xi));
            float twoxy = -2.f * dmx;                    // 2*dot(-mu, x)
            float ca    = 1.f + twoxy + xi2;             // coeff of (-mu)
            float den   = 1.f + twoxy + mu2 * xi2;
            float id    = 1.f / fmaxf(den, MIN_NORM);
            float4 w = make_float4((cb * xi.x - ca * mu4.x) * id,
                                   (cb * xi.y - ca * mu4.y) * id,
                                   (cb * xi.z - ca * mu4.z) * id,
                                   (cb * xi.w - ca * mu4.w) * id);
            float w2 = grp8(dot4(w, w));
            if constexpr (MODE == 1) {
                float n = fminf(fmaxf(sqrtf(w2), MIN_NORM), MAX_NORM);
                float s = cb * atanhf(n) / n;
                a.x += s * w.x; a.y += s * w.y; a.z += s * w.z; a.w += s * w.w;
            } else {
                float n = fminf(sqrtf(w2), MAX_NORM);
                float d = 2.f * atanhf(n);
                if (l8 == 0) av += d * d;
            }
        }
    }

    if constexpr (MODE != 2) {
        __shared__ float sh[32];
        if (threadIdx.x < 32) sh[threadIdx.x] = 0.f;
        __syncthreads();
        // butterfly across the 8 groups of this wave (all lanes end with wave-total)
        a.x += __shfl_xor(a.x, 8);  a.y += __shfl_xor(a.y, 8);
        a.z += __shfl_xor(a.z, 8);  a.w += __shfl_xor(a.w, 8);
        a.x += __shfl_xor(a.x, 16); a.y += __shfl_xor(a.y, 16);
        a.z += __shfl_xor(a.z, 16); a.w += __shfl_xor(a.w, 16);
        a.x += __shfl_xor(a.x, 32); a.y += __shfl_xor(a.y, 32);
        a.z += __shfl_xor(a.z, 32); a.w += __shfl_xor(a.w, 32);
        if ((threadIdx.x & 63) < 8) {
            atomicAdd(&sh[l8 * 4 + 0], a.x);
            atomicAdd(&sh[l8 * 4 + 1], a.y);
            atomicAdd(&sh[l8 * 4 + 2], a.z);
            atomicAdd(&sh[l8 * 4 + 3], a.w);
        }
        __syncthreads();
        if (threadIdx.x < 32) atomicAdd(&acc[threadIdx.x], sh[threadIdx.x]);
    } else {
        __shared__ float shv[4];
        for (int s = 1; s < 64; s <<= 1) av += __shfl_xor(av, s);
        if ((threadIdx.x & 63) == 0) shv[threadIdx.x >> 6] = av;
        __syncthreads();
        if (threadIdx.x == 0) atomicAdd(&acc[0], shv[0] + shv[1] + shv[2] + shv[3]);
    }
}

__global__ void init_kernel(float* ws) {
    if (threadIdx.x < 33) ws[threadIdx.x] = 0.f;   // acc[0..31], accv
}

// mu = exp0(acc/N); acc = 0
__global__ void finish_init_kernel(float* acc, float* mu, float invN) {
    int l = threadIdx.x;          // 0..31
    float v = acc[l] * invN;
    float n = fmaxf(sqrtf(sum32(v * v)), MIN_NORM);
    mu[l] = tanhf(n) * v / n;
    acc[l] = 0.f;
}

// mu = exp_map(mu, acc/N); acc = 0
__global__ void finish_iter_kernel(float* acc, float* mu, float invN) {
    int l = threadIdx.x;          // 0..31
    float v   = acc[l] * invN;
    float m   = mu[l];
    float mu2 = sum32(m * m);
    float nv  = fmaxf(sqrtf(sum32(v * v)), MIN_NORM);
    float t   = tanhf(nv / (1.f - mu2)) / nv;
    float u   = t * v;                         // u = tanh(|v|/(1-|mu|^2)) * v/|v|
    float u2  = sum32(u * u);
    float xy  = sum32(m * u);
    float num = (1.f + 2.f * xy + u2) * m + (1.f - mu2) * u;
    float den = 1.f + 2.f * xy + mu2 * u2;
    mu[l] = num / fmaxf(den, MIN_NORM);
    acc[l] = 0.f;
}

// factor = var_param/sqrt(var+eps); onm = exp0(mean_param); out_tail = mu
__global__ void finish_var_kernel(float* accv, const float* var_param,
                                  const float* mean_param, const float* mu,
                                  float invN, float* fct, float* onm, float* out_tail) {
    int l = threadIdx.x;          // 0..31
    float mp = mean_param[l];
    float n  = fmaxf(sqrtf(sum32(mp * mp)), MIN_NORM);
    onm[l] = tanhf(n) * mp / n;
    out_tail[l] = mu[l];
    if (l == 0) {
        float var = accv[0] * invN;
        fct[0] = var_param[0] / sqrtf(var + EPSF);
        accv[0] = 0.f;
    }
}

// out_i = mobius_add(onm, mobius_scalar_mul(factor, mobius_add(-mu, x_i)))
__global__ __launch_bounds__(256) void transform_kernel(const float4* __restrict__ x4,
                                                        const float* __restrict__ muv,
                                                        const float* __restrict__ fct,
                                                        const float* __restrict__ onmv,
                                                        float4* __restrict__ out4,
                                                        int nrows)
{
    const int l8   = threadIdx.x & 7;
    const int grp0 = (int)(blockIdx.x * blockDim.x + threadIdx.x) >> 3;
    const int ngrp = (int)(gridDim.x * blockDim.x) >> 3;

    float4 mu4 = reinterpret_cast<const float4*>(muv)[l8];
    float  mu2 = grp8(dot4(mu4, mu4));
    float  cb  = 1.f - mu2;
    float4 m4  = reinterpret_cast<const float4*>(onmv)[l8];
    float  m2  = grp8(dot4(m4, m4));
    float  r   = fct[0];

    for (int row = grp0; row < nrows; row += ngrp) {
        float4 xi = x4[row * 8 + l8];
        // w = mobius_add(-mu, x)
        float xi2   = grp8(dot4(xi, xi));
        float dmx   = grp8(dot4(mu4, xi));
        float twoxy = -2.f * dmx;
        float ca    = 1.f + twoxy + xi2;
        float den   = 1.f + twoxy + mu2 * xi2;
        float id    = 1.f / fmaxf(den, MIN_NORM);
        float4 w = make_float4((cb * xi.x - ca * mu4.x) * id,
                               (cb * xi.y - ca * mu4.y) * id,
                               (cb * xi.z - ca * mu4.z) * id,
                               (cb * xi.w - ca * mu4.w) * id);
        float w2 = grp8(dot4(w, w));
        // x_scaled = tanh(r*atanh(nw)) * w/nw = s*w
        float nw = fminf(fmaxf(sqrtf(w2), MIN_NORM), MAX_NORM);
        float s  = tanhf(r * atanhf(nw)) / nw;
        // out = mobius_add(onm, s*w); dot(onm,xs)=s*dot(onm,w); |xs|^2=s^2*w2
        float dmw = grp8(dot4(m4, w));
        float xy2 = s * dmw;
        float xs2 = s * s * w2;
        float ca2 = 1.f + 2.f * xy2 + xs2;       // coeff of onm
        float cb2 = (1.f - m2) * s;              // coeff of w
        float den2 = 1.f + 2.f * xy2 + m2 * xs2;
        float id2  = 1.f / fmaxf(den2, MIN_NORM);
        float4 o = make_float4((ca2 * m4.x + cb2 * w.x) * id2,
                               (ca2 * m4.y + cb2 * w.y) * id2,
                               (ca2 * m4.z + cb2 * w.z) * id2,
                               (ca2 * m4.w + cb2 * w.w) * id2);
        out4[row * 8 + l8] = o;
    }
}

extern "C" void kernel_launch(void* const* d_in, const int* in_sizes, int n_in,
                              void* d_out, int out_size, void* d_ws, size_t ws_size,
                              hipStream_t stream) {
    const float* x          = (const float*)d_in[0];
    const float* mean_param = (const float*)d_in[1];
    const float* var_param  = (const float*)d_in[2];
    float* out = (float*)d_out;
    float* ws  = (float*)d_ws;

    float* acc  = ws;        // [32]
    float* accv = ws + 32;   // [1]
    float* mu   = ws + 64;   // [32]
    float* fct  = ws + 96;   // [1]
    float* onm  = ws + 128;  // [32]

    const int N = in_sizes[0] / 32;
    const float invN = 1.f / (float)N;
    const float4* x4 = (const float4*)x;

    const int G = 2048, B = 256;

    init_kernel<<<1, 64, 0, stream>>>(ws);

    reduce_kernel<0><<<G, B, 0, stream>>>(x4, nullptr, acc, N);
    finish_init_kernel<<<1, 32, 0, stream>>>(acc, mu, invN);

    for (int it = 0; it < 10; ++it) {
        reduce_kernel<1><<<G, B, 0, stream>>>(x4, mu, acc, N);
        finish_iter_kernel<<<1, 32, 0, stream>>>(acc, mu, invN);
    }

    reduce_kernel<2><<<G, B, 0, stream>>>(x4, mu, accv, N);
    finish_var_kernel<<<1, 32, 0, stream>>>(accv, var_param, mean_param, mu, invN,
                                            fct, onm, out + (size_t)N * 32);

    transform_kernel<<<G, B, 0, stream>>>(x4, mu, fct, onm, (float4*)out, N);
}